// Round 13
// baseline (48.038 us; speedup 1.0000x reference)
//
#include <hip/hip_runtime.h>
#include <hip/hip_bf16.h>
#include <math.h>

typedef __attribute__((ext_vector_type(8))) __bf16 bf16x8;
typedef __attribute__((ext_vector_type(4))) float f32x4;

constexpr float VX_ = 0.2f;
constexpr float VY_ = 0.2f;
constexpr float X_OFF_ = 0.1f;    // VX/2 + 0.0
constexpr float Y_OFF_ = -39.9f;  // VY/2 - 40.0
constexpr float EPS_ = 1e-3f;

#define S1 512    // kA block count
#define NREP 64   // accumulator replicas; 512/64 = 8-deep atomics per address

__device__ __forceinline__ float wave_sum(float v) {
#pragma unroll
  for (int off = 32; off; off >>= 1) v += __shfl_xor(v, off);
  return v;
}

__device__ __forceinline__ ushort bf16bits(float x) {
  __hip_bfloat16 h = __float2bfloat16(x);
  return __builtin_bit_cast(ushort, h);
}

// packed RNE f32x2 -> bf16x2 (gfx950 has the instruction but no builtin)
__device__ __forceinline__ uint32_t cvtpk(float lo, float hi) {
  uint32_t r;
  asm("v_cvt_pk_bf16_f32 %0, %1, %2" : "=v"(r) : "v"(lo), "v"(hi));
  return r;
}

// kzero: zero accrep[NREP][128] (capture-safe replacement for memset).
__global__ __launch_bounds__(512) void kzero(float* __restrict__ accrep) {
  const int i = blockIdx.x * 512 + threadIdx.x;
  if (i < NREP * 128) accrep[i] = 0.f;
}

// kA: inline concurrent prep (W->LDS, G' = scaled W^T W + wsum) + per-n
// moments pre-contracted to 2 floats/thread + per-pillar aux
// {m0,m1,m2,ox,oy,np} for kB. Block-reduce, then atomicAdd into
// accrep[blockIdx % NREP][128] (8-deep per address -> negligible).
__global__ __launch_bounds__(256) void kA_moments(
    const float* __restrict__ feats, const int* __restrict__ npts_arr,
    const int* __restrict__ coors, const float* __restrict__ W,
    float* __restrict__ accrep, float* __restrict__ aux, int P) {
  __shared__ float W_lds[576];
  __shared__ float gws[54];  // G'[45] (off-diag doubled) + wsum[9]
  __shared__ float2 red[4][64];
  const int t = threadIdx.x, lane = t & 63, wv = t >> 6;

  for (int i = t; i < 576; i += 256) W_lds[i] = W[i];
  __syncthreads();
  if (t < 180) {  // G': 45 pairs x 4-way split over o
    const int pr = t >> 2, k = t & 3;
    int c = 0, rem = pr;
    while (rem >= 9 - c) {
      rem -= 9 - c;
      ++c;
    }
    const int c2 = c + rem;
    float s = 0.f;
    for (int o = k * 16; o < k * 16 + 16; ++o)
      s += W_lds[o * 9 + c] * W_lds[o * 9 + c2];
    s += __shfl_xor(s, 1);
    s += __shfl_xor(s, 2);
    if (k == 0) gws[pr] = (c == c2) ? s : 2.f * s;
  } else if (t < 216) {  // wsum: 9 cols x 4-way split
    const int tt = t - 180, c = tt >> 2, k = tt & 3;
    float s = 0.f;
    for (int o = k * 16; o < k * 16 + 16; ++o) s += W_lds[o * 9 + c];
    s += __shfl_xor(s, 1);
    s += __shfl_xor(s, 2);
    if (k == 0) gws[45 + c] = s;
  }
  __syncthreads();
  float g[45], wsv[9];
#pragma unroll
  for (int i = 0; i < 45; ++i) g[i] = gws[i];
#pragma unroll
  for (int i = 0; i < 9; ++i) wsv[i] = gws[45 + i];

  float s1 = 0.f, s2 = 0.f;
  const int nw = S1 * 4;
  int p = blockIdx.x * 4 + wv;
  if (p < P) {
    float4 f =
        *reinterpret_cast<const float4*>(feats + (size_t)p * 256 + lane * 4);
    int np = npts_arr[p];
    int cx = coors[p * 4 + 3], cy = coors[p * 4 + 2];
    while (true) {
      const int p2 = p + nw;
      const bool has2 = p2 < P;
      float4 f2 = make_float4(0.f, 0.f, 0.f, 0.f);
      int np2 = 1, cx2 = 0, cy2 = 0;
      if (has2) {  // prefetch next pillar
        f2 = *reinterpret_cast<const float4*>(feats + (size_t)p2 * 256 +
                                              lane * 4);
        np2 = npts_arr[p2];
        cx2 = coors[p2 * 4 + 3];
        cy2 = coors[p2 * 4 + 2];
      }
      const float ox = (float)cx * VX_ + X_OFF_;
      const float oy = (float)cy * VY_ + Y_OFF_;
      const float inv = 1.f / (float)np;
      const float m0 = wave_sum(f.x) * inv;
      const float m1 = wave_sum(f.y) * inv;
      const float m2 = wave_sum(f.z) * inv;
      if (lane == 0) {  // per-pillar aux for kB (fire-and-forget stores)
        *reinterpret_cast<float4*>(aux + (size_t)p * 8) =
            make_float4(m0, m1, m2, ox);
        *reinterpret_cast<float4*>(aux + (size_t)p * 8 + 4) =
            make_float4(oy, __int_as_float(np), 0.f, 0.f);
      }
      const bool valid = lane < np;
      float ft[9] = {f.x,      f.y,      f.z,      f.w,      f.x - m0,
                     f.y - m1, f.z - m2, f.x - ox, f.y - oy};
#pragma unroll
      for (int c = 0; c < 9; ++c) ft[c] = valid ? ft[c] : 0.f;
      int idx = 0;
      float t1 = 0.f, t2 = 0.f;
#pragma unroll
      for (int c = 0; c < 9; ++c) {
        float u = 0.f;
#pragma unroll
        for (int c2 = c; c2 < 9; ++c2) u = fmaf(g[idx++], ft[c2], u);
        t2 = fmaf(ft[c], u, t2);
        t1 = fmaf(ft[c], wsv[c], t1);
      }
      s1 += t1;
      s2 += t2;
      if (!has2) break;
      p = p2;
      f = f2;
      np = np2;
      cx = cx2;
      cy = cy2;
    }
  }
  red[wv][lane] = make_float2(s1, s2);
  __syncthreads();
  if (t < 128) {
    const int n = t & 63, j = t >> 6;
    const float v = (j == 0)
                        ? (red[0][n].x + red[1][n].x + red[2][n].x + red[3][n].x)
                        : (red[0][n].y + red[1][n].y + red[2][n].y + red[3][n].y);
    atomicAdd(&accrep[(blockIdx.x & (NREP - 1)) * 128 + t], v);
  }
}

// kB: light stats prologue (32 KB coalesced accrep reduce -> a[n],b[n]),
// then the proven MFMA main loop (R12): A = masked bf16 feat rows staged
// via LDS, B fragments from W_lds, fused BN+relu+max epilogue.
__global__ __launch_bounds__(256) void kB_mfma(
    const float* __restrict__ feats, const float* __restrict__ aux,
    const float* __restrict__ W, const float* __restrict__ gamma,
    const float* __restrict__ beta, const float* __restrict__ accrep,
    float* __restrict__ out, int P) {
  __shared__ float W_lds[576];
  __shared__ uint32_t A_lds[4][64][20];  // rows padded to 80 B
  __shared__ float2 shab[64];
  const int t = threadIdx.x, lane = t & 63, wv = t >> 6;
  const int g16 = lane >> 4, l16 = lane & 15;

  for (int i = t; i < 576; i += 256) W_lds[i] = W[i];
  // zero the permanently-zero k-slots of this wave's A rows (once)
  A_lds[wv][lane][6] = 0u;
  A_lds[wv][lane][7] = 0u;
  *reinterpret_cast<uint4*>(&A_lds[wv][lane][8]) = make_uint4(0u, 0u, 0u, 0u);
  *reinterpret_cast<uint4*>(&A_lds[wv][lane][12]) = make_uint4(0u, 0u, 0u, 0u);

  // ---- stats prologue: reduce accrep[NREP][128] (coalesced, unroll 4) ----
  float ssum = 0.f;
  if (t < 128) {
    float a0 = 0.f, a1 = 0.f, a2 = 0.f, a3 = 0.f;
#pragma unroll
    for (int r = 0; r < NREP; r += 4) {
      a0 += accrep[(r + 0) * 128 + t];
      a1 += accrep[(r + 1) * 128 + t];
      a2 += accrep[(r + 2) * 128 + t];
      a3 += accrep[(r + 3) * 128 + t];
    }
    ssum = (a0 + a1) + (a2 + a3);
  }
  __syncthreads();
  if (t < 128) {
    // stash sums in shab via two halves: t<64 -> sum x (n=t), else sum x^2
    if (t < 64) shab[t].x = ssum;
    else shab[t - 64].y = ssum;
  }
  __syncthreads();
  if (t < 64) {
    const float sx = shab[t].x, sxx = shab[t].y;
    const float invPN = 1.f / ((float)P * 64.f);
    const float mu = sx * invPN;
    const float var = sxx * invPN - mu * mu;
    const float a = gamma[t] * rsqrtf(var + EPS_);
    shab[t] = make_float2(a, beta[t] - mu * a);
  }
  __syncthreads();

  // B fragments from W_lds
  uint4 bq[4];
#pragma unroll
  for (int nt = 0; nt < 4; ++nt) {
    const int col = nt * 16 + l16;
    ushort h[8];
#pragma unroll
    for (int j = 0; j < 8; ++j) {
      const int kk = 8 * g16 + j;
      h[j] = (kk < 9) ? bf16bits(W_lds[col * 9 + kk]) : (ushort)0;
    }
    bq[nt].x = (uint)h[0] | ((uint)h[1] << 16);
    bq[nt].y = (uint)h[2] | ((uint)h[3] << 16);
    bq[nt].z = (uint)h[4] | ((uint)h[5] << 16);
    bq[nt].w = (uint)h[6] | ((uint)h[7] << 16);
  }

  float ar[16], br[16];
#pragma unroll
  for (int i = 0; i < 16; ++i) {
    const int n = (i >> 2) * 16 + g16 * 4 + (i & 3);
    const float2 v = shab[n];
    ar[i] = v.x;
    br[i] = v.y;
  }

  const int stride = gridDim.x * 4;
  int p = blockIdx.x * 4 + wv;
  if (p >= P) return;
  float4 f = *reinterpret_cast<const float4*>(feats + (size_t)p * 256 + lane * 4);
  float4 a0 = *reinterpret_cast<const float4*>(aux + (size_t)p * 8);
  float4 a1 = *reinterpret_cast<const float4*>(aux + (size_t)p * 8 + 4);
  while (true) {
    const int p2 = p + stride;
    const bool has2 = p2 < P;
    float4 f2 = make_float4(0.f, 0.f, 0.f, 0.f);
    float4 a0b = make_float4(0.f, 0.f, 0.f, 0.f);
    float4 a1b = make_float4(0.f, 0.f, 0.f, 0.f);
    if (has2) {  // prefetch next pillar (feat row + aux)
      f2 = *reinterpret_cast<const float4*>(feats + (size_t)p2 * 256 + lane * 4);
      a0b = *reinterpret_cast<const float4*>(aux + (size_t)p2 * 8);
      a1b = *reinterpret_cast<const float4*>(aux + (size_t)p2 * 8 + 4);
    }
    const float m0 = a0.x, m1 = a0.y, m2 = a0.z, ox = a0.w, oy = a1.x;
    const int np = __float_as_int(a1.y);
    const bool valid = lane < np;
    const float v0 = valid ? f.x : 0.f;
    const float v1 = valid ? f.y : 0.f;
    const float v2 = valid ? f.z : 0.f;
    const float v3 = valid ? f.w : 0.f;
    const float v4 = valid ? f.x - m0 : 0.f;
    const float v5 = valid ? f.y - m1 : 0.f;
    const float v6 = valid ? f.z - m2 : 0.f;
    const float v7 = valid ? f.x - ox : 0.f;
    const float v8 = valid ? f.y - oy : 0.f;
    union {
      uint32_t u[6];
      uint4 q;
    } pk;
    pk.u[0] = cvtpk(v0, v1);
    pk.u[1] = cvtpk(v2, v3);
    pk.u[2] = cvtpk(v4, v5);
    pk.u[3] = cvtpk(v6, v7);
    pk.u[4] = cvtpk(v8, 0.f);
    // stage this lane's A row (lane == n); same-wave ds_write->ds_read is
    // in-order and each wave owns its A_lds[wv] region: no barrier needed.
    *reinterpret_cast<uint4*>(&A_lds[wv][lane][0]) = pk.q;
    *reinterpret_cast<uint2*>(&A_lds[wv][lane][4]) = make_uint2(pk.u[4], 0u);

    bf16x8 afr[4];
#pragma unroll
    for (int mt = 0; mt < 4; ++mt) {
      afr[mt] =
          *reinterpret_cast<const bf16x8*>(&A_lds[wv][mt * 16 + l16][g16 * 4]);
    }
    const f32x4 accz = {0.f, 0.f, 0.f, 0.f};
    float mx[4] = {0.f, 0.f, 0.f, 0.f};  // init 0 == fused relu
#pragma unroll
    for (int mt = 0; mt < 4; ++mt) {
      const bf16x8 a = afr[mt];
#pragma unroll
      for (int nt = 0; nt < 4; ++nt) {
        f32x4 acc4 = __builtin_amdgcn_mfma_f32_16x16x32_bf16(
            a, __builtin_bit_cast(bf16x8, bq[nt]), accz, 0, 0, 0);
#pragma unroll
        for (int r = 0; r < 4; ++r) {
          const float y = fmaf(acc4[r], ar[mt * 4 + r], br[mt * 4 + r]);
          mx[nt] = fmaxf(mx[nt], y);
        }
      }
    }
#pragma unroll
    for (int nt = 0; nt < 4; ++nt) {
      mx[nt] = fmaxf(mx[nt], __shfl_xor(mx[nt], 16));
      mx[nt] = fmaxf(mx[nt], __shfl_xor(mx[nt], 32));
    }
    const float outv =
        (g16 == 0) ? mx[0] : (g16 == 1) ? mx[1] : (g16 == 2) ? mx[2] : mx[3];
    out[(size_t)p * 64 + lane] = outv;  // o = g16*16 + l16 == lane
    if (!has2) break;
    p = p2;
    f = f2;
    a0 = a0b;
    a1 = a1b;
  }
}

extern "C" void kernel_launch(void* const* d_in, const int* in_sizes, int n_in,
                              void* d_out, int out_size, void* d_ws,
                              size_t ws_size, hipStream_t stream) {
  const float* feats = (const float*)d_in[0];
  const int* npts = (const int*)d_in[1];
  const int* coors = (const int*)d_in[2];
  const float* W = (const float*)d_in[3];
  const float* gamma = (const float*)d_in[4];
  const float* beta = (const float*)d_in[5];
  float* out = (float*)d_out;
  float* ws = (float*)d_ws;

  const int P = in_sizes[1];  // num_points has P elements

  float* accrep = ws;                 // [NREP][128]
  float* aux = ws + NREP * 128;       // [8*P]: per-pillar aux

  kzero<<<(NREP * 128 + 511) / 512, 512, 0, stream>>>(accrep);
  kA_moments<<<S1, 256, 0, stream>>>(feats, npts, coors, W, accrep, aux, P);
  const int nb = (P + 15) / 16;  // 4 waves/block, ~4 pillars/wave
  kB_mfma<<<nb, 256, 0, stream>>>(feats, aux, W, gamma, beta, accrep, out, P);
}